// Round 1
// baseline (1968.351 us; speedup 1.0000x reference)
//
#include <hip/hip_runtime.h>
#include <cstdint>

#define NN_NODES 2100
#define CH 256

// ---------------------------------------------------------------------------
// conv1x1 + BN + ReLU + avgpool2  ->  h0[b, noff + gi*W2 + gj, o]
// x: (8, K, H, W) fp32.  dw: (256, K).  Output written in node-major (b,n,c).
// Block: 64 out-channels x 16 pooled pixels (64 full-res pixels), 256 threads,
// 4x4 microtile; thread's 4 N-columns are exactly the 4 sub-pixels of one
// pooled output -> relu+average in registers in the epilogue.
// ---------------------------------------------------------------------------
__global__ __launch_bounds__(256)
void conv_bn_pool_kernel(const float* __restrict__ x, const float* __restrict__ dw,
                         const float* __restrict__ db, const float* __restrict__ gg,
                         const float* __restrict__ bb, const float* __restrict__ mm,
                         const float* __restrict__ vv, float* __restrict__ h0,
                         int K, int H, int W, int noff)
{
    const int W2 = W >> 1;
    const int tilesPerRow = (W2 + 15) >> 4;
    const int gi  = blockIdx.x / tilesPerRow;
    const int gj0 = (blockIdx.x % tilesPerRow) << 4;
    const int o0  = blockIdx.y << 6;
    const int b   = blockIdx.z;

    __shared__ float Xs[32][68];
    __shared__ float Ws[32][68];

    const int t  = threadIdx.x;
    const int tx = t & 15;
    const int ty = t >> 4;

    float acc[4][4];
#pragma unroll
    for (int r = 0; r < 4; ++r)
#pragma unroll
        for (int s = 0; s < 4; ++s) acc[r][s] = 0.0f;

    const size_t HW = (size_t)H * W;
    const float* xb = x + (size_t)b * K * HW;
    const int r0 = gi << 1;
    const int c0 = gj0 << 1;

    for (int k0 = 0; k0 < K; k0 += 32) {
        // X tile: 32 channels x (2 rows x 32 cols full-res). Coalesced along cols.
#pragma unroll
        for (int it = 0; it < 8; ++it) {
            int lin  = (it << 8) + t;
            int c_l  = lin >> 6;
            int rest = lin & 63;
            int r_l  = rest >> 5;
            int col  = rest & 31;
            int cc   = c0 + col;
            float val = 0.0f;
            if (cc < W) val = xb[(size_t)(k0 + c_l) * HW + (size_t)(r0 + r_l) * W + cc];
            // p = pooled-block*4 + sub (sub = di*2+dj)
            int p = ((col >> 1) << 2) + (r_l << 1) + (col & 1);
            Xs[c_l][p] = val;
        }
        // W tile: Ws[k][o_local]
#pragma unroll
        for (int it = 0; it < 8; ++it) {
            int lin = (it << 8) + t;
            int o_l = lin >> 5;
            int k_l = lin & 31;
            Ws[k_l][o_l] = dw[(size_t)(o0 + o_l) * K + (k0 + k_l)];
        }
        __syncthreads();
#pragma unroll
        for (int k = 0; k < 32; ++k) {
            const float4 av = *(const float4*)&Ws[k][ty << 2];
            const float4 bv = *(const float4*)&Xs[k][tx << 2];
            acc[0][0] += av.x * bv.x; acc[0][1] += av.x * bv.y; acc[0][2] += av.x * bv.z; acc[0][3] += av.x * bv.w;
            acc[1][0] += av.y * bv.x; acc[1][1] += av.y * bv.y; acc[1][2] += av.y * bv.z; acc[1][3] += av.y * bv.w;
            acc[2][0] += av.z * bv.x; acc[2][1] += av.z * bv.y; acc[2][2] += av.z * bv.z; acc[2][3] += av.z * bv.w;
            acc[3][0] += av.w * bv.x; acc[3][1] += av.w * bv.y; acc[3][2] += av.w * bv.z; acc[3][3] += av.w * bv.w;
        }
        __syncthreads();
    }

    const int gj = gj0 + tx;
    if (gj < W2) {
        const int node = noff + gi * W2 + gj;
        float* dst = h0 + ((size_t)b * NN_NODES + node) * CH + o0 + (ty << 2);
#pragma unroll
        for (int r = 0; r < 4; ++r) {
            const int o = o0 + (ty << 2) + r;
            const float scale = gg[o] * rsqrtf(vv[o] + 1e-5f);
            const float shift = (db[o] - mm[o]) * scale + bb[o];
            float sum = 0.0f;
#pragma unroll
            for (int s = 0; s < 4; ++s)
                sum += fmaxf(acc[r][s] * scale + shift, 0.0f);
            dst[r] = sum * 0.25f;
        }
    }
}

// ---------------------------------------------------------------------------
// GNN aggregation (gather form). Neighbor lists + degrees are analytic:
//   ctx graph: 8-connected within each grid + self-loop
//   hier graph: parent<->4 children between adjacent scales + self-loop
// Block = 1 node (256 channels = 256 threads), loops over the 8 batches.
// ---------------------------------------------------------------------------
__global__ __launch_bounds__(256)
void gnn_gather_kernel(const float* __restrict__ h, float* __restrict__ agg, int hier)
{
    const int n = blockIdx.x;
    const int c = threadIdx.x;
    int nbr[9];
    int cnt = 0;
    int gw, off;
    if (n < 1600)      { gw = 40; off = 0; }
    else if (n < 2000) { gw = 20; off = 1600; }
    else               { gw = 10; off = 2000; }
    const int loc = n - off;
    const int i = loc / gw;
    const int j = loc - i * gw;
    if (!hier) {
#pragma unroll
        for (int di = -1; di <= 1; ++di)
#pragma unroll
            for (int dj = -1; dj <= 1; ++dj) {
                int ii = i + di, jj = j + dj;
                if (ii >= 0 && ii < gw && jj >= 0 && jj < gw)
                    nbr[cnt++] = off + ii * gw + jj;
            }
    } else {
        nbr[cnt++] = n;                                  // self-loop
        if (off == 0) {                                  // 40-grid: parent in 20-grid
            nbr[cnt++] = 1600 + (i >> 1) * 20 + (j >> 1);
        } else if (off == 1600) {                        // 20-grid: parent + 4 children
            nbr[cnt++] = 2000 + (i >> 1) * 10 + (j >> 1);
#pragma unroll
            for (int di = 0; di < 2; ++di)
#pragma unroll
                for (int dj = 0; dj < 2; ++dj)
                    nbr[cnt++] = ((i << 1) + di) * 40 + ((j << 1) + dj);
        } else {                                         // 10-grid: 4 children
#pragma unroll
            for (int di = 0; di < 2; ++di)
#pragma unroll
                for (int dj = 0; dj < 2; ++dj)
                    nbr[cnt++] = 1600 + ((i << 1) + di) * 20 + ((j << 1) + dj);
        }
    }
    const float inv = 1.0f / (float)cnt;
    for (int b = 0; b < 8; ++b) {
        float sum = 0.0f;
        for (int e = 0; e < cnt; ++e)
            sum += h[((size_t)b * NN_NODES + nbr[e]) * CH + c];
        agg[((size_t)b * NN_NODES + n) * CH + c] = sum * inv;
    }
}

// ---------------------------------------------------------------------------
// GNN dense layer: out = relu(A @ Wg + bg).  A: (M,256), Wg: (256,256).
// ---------------------------------------------------------------------------
__global__ __launch_bounds__(256)
void gnn_gemm_kernel(const float* __restrict__ A, const float* __restrict__ Wg,
                     const float* __restrict__ bg, float* __restrict__ out, int M)
{
    const int row0 = blockIdx.x << 6;
    const int d0   = blockIdx.y << 6;
    __shared__ float As[32][68];
    __shared__ float Bs[32][68];
    const int t = threadIdx.x, tx = t & 15, ty = t >> 4;
    float acc[4][4];
#pragma unroll
    for (int r = 0; r < 4; ++r)
#pragma unroll
        for (int s = 0; s < 4; ++s) acc[r][s] = 0.0f;

    for (int k0 = 0; k0 < 256; k0 += 32) {
#pragma unroll
        for (int it = 0; it < 8; ++it) {
            int lin = (it << 8) + t;
            int r = lin >> 5, k = lin & 31;
            int row = row0 + r;
            As[k][r] = (row < M) ? A[(size_t)row * 256 + k0 + k] : 0.0f;
        }
#pragma unroll
        for (int it = 0; it < 8; ++it) {
            int lin = (it << 8) + t;
            int k = lin >> 6, d = lin & 63;
            Bs[k][d] = Wg[(size_t)(k0 + k) * 256 + d0 + d];
        }
        __syncthreads();
#pragma unroll
        for (int k = 0; k < 32; ++k) {
            const float4 av = *(const float4*)&As[k][ty << 2];
            const float4 bv = *(const float4*)&Bs[k][tx << 2];
            acc[0][0] += av.x * bv.x; acc[0][1] += av.x * bv.y; acc[0][2] += av.x * bv.z; acc[0][3] += av.x * bv.w;
            acc[1][0] += av.y * bv.x; acc[1][1] += av.y * bv.y; acc[1][2] += av.y * bv.z; acc[1][3] += av.y * bv.w;
            acc[2][0] += av.z * bv.x; acc[2][1] += av.z * bv.y; acc[2][2] += av.z * bv.z; acc[2][3] += av.z * bv.w;
            acc[3][0] += av.w * bv.x; acc[3][1] += av.w * bv.y; acc[3][2] += av.w * bv.z; acc[3][3] += av.w * bv.w;
        }
        __syncthreads();
    }
    const int d = d0 + (tx << 2);
    const float4 bgv = *(const float4*)&bg[d];
#pragma unroll
    for (int r = 0; r < 4; ++r) {
        int row = row0 + (ty << 2) + r;
        if (row < M) {
            float4 v;
            v.x = fmaxf(acc[r][0] + bgv.x, 0.0f);
            v.y = fmaxf(acc[r][1] + bgv.y, 0.0f);
            v.z = fmaxf(acc[r][2] + bgv.z, 0.0f);
            v.w = fmaxf(acc[r][3] + bgv.w, 0.0f);
            *(float4*)&out[(size_t)row * 256 + d] = v;
        }
    }
}

// ---------------------------------------------------------------------------
// convT2x2 + bias + residual.  A-row (per pixel) is built on the fly:
//   a[c] = h0[b,n,c] + h6[b,n,c] (+ h6[b,parent,c] for the up2 term)
// B = tW viewed as (256, Cout*4).  Epilogue scatters the 2x2 block and adds
// the matching feat residual.
// ---------------------------------------------------------------------------
__global__ __launch_bounds__(256)
void convt_add_kernel(const float* __restrict__ h0, const float* __restrict__ h6,
                      const float* __restrict__ tW, const float* __restrict__ tb,
                      const float* __restrict__ feat, float* __restrict__ out,
                      int Cout, int H2, int noff, int pbase, int pw)
{
    const int pp = H2 * H2;
    const int M = 8 * pp;
    const int Ncol = Cout << 2;
    const int row0 = blockIdx.x << 6;
    const int col0 = blockIdx.y << 6;
    __shared__ float As[32][68];
    __shared__ float Bs[32][68];
    const int t = threadIdx.x, tx = t & 15, ty = t >> 4;
    float acc[4][4];
#pragma unroll
    for (int r = 0; r < 4; ++r)
#pragma unroll
        for (int s = 0; s < 4; ++s) acc[r][s] = 0.0f;

    for (int k0 = 0; k0 < 256; k0 += 32) {
#pragma unroll
        for (int it = 0; it < 8; ++it) {
            int lin = (it << 8) + t;
            int r = lin >> 5, k = lin & 31;
            int row = row0 + r;
            float val = 0.0f;
            if (row < M) {
                int b   = row / pp;
                int pix = row - b * pp;
                size_t base = ((size_t)b * NN_NODES + noff + pix) * CH + k0 + k;
                val = h0[base] + h6[base];
                if (pbase >= 0) {
                    int i = pix / H2;
                    int j = pix - i * H2;
                    int pn = pbase + (i >> 1) * pw + (j >> 1);
                    val += h6[((size_t)b * NN_NODES + pn) * CH + k0 + k];
                }
            }
            As[k][r] = val;
        }
#pragma unroll
        for (int it = 0; it < 8; ++it) {
            int lin = (it << 8) + t;
            int k = lin >> 6, d = lin & 63;
            Bs[k][d] = tW[(size_t)(k0 + k) * Ncol + col0 + d];
        }
        __syncthreads();
#pragma unroll
        for (int k = 0; k < 32; ++k) {
            const float4 av = *(const float4*)&As[k][ty << 2];
            const float4 bv = *(const float4*)&Bs[k][tx << 2];
            acc[0][0] += av.x * bv.x; acc[0][1] += av.x * bv.y; acc[0][2] += av.x * bv.z; acc[0][3] += av.x * bv.w;
            acc[1][0] += av.y * bv.x; acc[1][1] += av.y * bv.y; acc[1][2] += av.y * bv.z; acc[1][3] += av.y * bv.w;
            acc[2][0] += av.z * bv.x; acc[2][1] += av.z * bv.y; acc[2][2] += av.z * bv.z; acc[2][3] += av.z * bv.w;
            acc[3][0] += av.w * bv.x; acc[3][1] += av.w * bv.y; acc[3][2] += av.w * bv.z; acc[3][3] += av.w * bv.w;
        }
        __syncthreads();
    }

    const int col = col0 + (tx << 2);   // col = o*4 + k*2 + l ; thread's 4 cols share o
    const int o = col >> 2;
    const int H = H2 << 1;
    const float tbo = tb[o];
#pragma unroll
    for (int r = 0; r < 4; ++r) {
        int row = row0 + (ty << 2) + r;
        if (row < M) {
            int b   = row / pp;
            int pix = row - b * pp;
            int i = pix / H2;
            int j = pix - i * H2;
            size_t obase = (((size_t)b * Cout + o) * (size_t)H + (i << 1)) * H + (j << 1);
#pragma unroll
            for (int s = 0; s < 4; ++s) {
                size_t a = obase + (size_t)((s >> 1) * H + (s & 1));
                out[a] = acc[r][s] + tbo + feat[a];
            }
        }
    }
}

extern "C" void kernel_launch(void* const* d_in, const int* in_sizes, int n_in,
                              void* d_out, int out_size, void* d_ws, size_t ws_size,
                              hipStream_t stream)
{
    const float* feat0 = (const float*)d_in[0];
    const float* feat1 = (const float*)d_in[1];
    const float* feat2 = (const float*)d_in[2];
    const float* feat3 = (const float*)d_in[3];
    const float* dw1 = (const float*)d_in[4];
    const float* db1 = (const float*)d_in[5];
    const float* g1  = (const float*)d_in[6];
    const float* b1  = (const float*)d_in[7];
    const float* m1  = (const float*)d_in[8];
    const float* v1  = (const float*)d_in[9];
    const float* dw2 = (const float*)d_in[10];
    const float* db2 = (const float*)d_in[11];
    const float* g2  = (const float*)d_in[12];
    const float* b2  = (const float*)d_in[13];
    const float* m2  = (const float*)d_in[14];
    const float* v2  = (const float*)d_in[15];
    const float* dw3 = (const float*)d_in[16];
    const float* db3 = (const float*)d_in[17];
    const float* g3  = (const float*)d_in[18];
    const float* b3  = (const float*)d_in[19];
    const float* m3  = (const float*)d_in[20];
    const float* v3  = (const float*)d_in[21];
    const float* gW[6]; const float* gb[6];
    for (int l = 0; l < 6; ++l) {
        gW[l] = (const float*)d_in[22 + 2 * l];
        gb[l] = (const float*)d_in[23 + 2 * l];
    }
    const float* tW1 = (const float*)d_in[34];
    const float* tb1 = (const float*)d_in[35];
    const float* tW2 = (const float*)d_in[36];
    const float* tb2 = (const float*)d_in[37];
    const float* tW3 = (const float*)d_in[38];
    const float* tb3 = (const float*)d_in[39];

    // workspace layout (floats): h0 | t1 | t2   (each 8*2100*256 = 4,300,800)
    float* h0 = (float*)d_ws;
    float* t1 = h0 + (size_t)8 * NN_NODES * CH;
    float* t2 = t1 + (size_t)8 * NN_NODES * CH;

    // feat0 passthrough
    hipMemcpyAsync(d_out, d_in[0], (size_t)52428800 * sizeof(float),
                   hipMemcpyDeviceToDevice, stream);

    dim3 blk(256);
    // conv1x1 + BN + ReLU + avgpool2 -> h0 (node-major)
    conv_bn_pool_kernel<<<dim3(3 * 40, 4, 8), blk, 0, stream>>>(
        feat1, dw1, db1, g1, b1, m1, v1, h0, 512, 80, 80, 0);
    conv_bn_pool_kernel<<<dim3(2 * 20, 4, 8), blk, 0, stream>>>(
        feat2, dw2, db2, g2, b2, m2, v2, h0, 1024, 40, 40, 1600);
    conv_bn_pool_kernel<<<dim3(1 * 10, 4, 8), blk, 0, stream>>>(
        feat3, dw3, db3, g3, b3, m3, v3, h0, 2048, 20, 20, 2000);

    // 6 GNN layers: ctx, ctx, hier, hier, ctx, ctx
    const int M = 8 * NN_NODES;
    const int types[6] = {0, 0, 1, 1, 0, 0};
    const float* hin = h0;
    for (int l = 0; l < 6; ++l) {
        gnn_gather_kernel<<<dim3(NN_NODES), blk, 0, stream>>>(hin, t1, types[l]);
        gnn_gemm_kernel<<<dim3((M + 63) / 64, 4), blk, 0, stream>>>(t1, gW[l], gb[l], t2, M);
        hin = t2;
    }

    // convT2x2 + bias + residual
    float* out1 = (float*)d_out + 52428800;
    float* out2 = out1 + 26214400;
    float* out3 = out2 + 13107200;
    convt_add_kernel<<<dim3(200, 32), blk, 0, stream>>>(
        h0, t2, tW1, tb1, feat1, out1, 512, 40, 0, 1600, 20);
    convt_add_kernel<<<dim3(50, 64), blk, 0, stream>>>(
        h0, t2, tW2, tb2, feat2, out2, 1024, 20, 1600, 2000, 10);
    convt_add_kernel<<<dim3(13, 128), blk, 0, stream>>>(
        h0, t2, tW3, tb3, feat3, out3, 2048, 10, 2000, -1, 0);
}

// Round 2
// 734.218 us; speedup vs baseline: 2.6809x; 2.6809x over previous
//
#include <hip/hip_runtime.h>
#include <cstdint>

#define NODES 2100

typedef __attribute__((ext_vector_type(8))) __bf16 bf16x8;
typedef __attribute__((ext_vector_type(4))) float f32x4;
typedef __attribute__((ext_vector_type(8))) unsigned short u16x8;

__device__ inline float bf2f(unsigned short s) { return __uint_as_float(((unsigned)s) << 16); }
__device__ inline unsigned short f2bf(float f) {
    unsigned u = __float_as_uint(f);
    u += 0x7fff + ((u >> 16) & 1);          // RNE
    return (unsigned short)(u >> 16);
}
__device__ inline void gload16(const unsigned short* g, void* lds) {
    __builtin_amdgcn_global_load_lds(
        (const __attribute__((address_space(1))) void*)g,
        (__attribute__((address_space(3))) void*)lds, 16, 0, 0);
}

// ---------------------------------------------------------------------------
// Shared MFMA GEMM core: C(128x128) += A(rows mA, k-contig) x B(rows = cols of
// logical B, k-contig).  BK=64, 256 threads = 4 waves (2x2), 4x4 frags/wave.
// ---------------------------------------------------------------------------
__device__ __attribute__((always_inline)) inline
void gemm_core(const unsigned short* __restrict__ A, const unsigned short* __restrict__ B,
               int K, int m0, int n0, int mClamp,
               unsigned short* As, unsigned short* Bs, f32x4 acc[4][4])
{
    const int t = threadIdx.x, lane = t & 63, w = t >> 6;
    const int wr = w >> 1, wc = w & 1;
    for (int k0 = 0; k0 < K; k0 += 64) {
#pragma unroll
        for (int i = 0; i < 4; ++i) {
            int LO = ((i << 8) + t) << 4;        // byte offset in tile
            int row = LO >> 7;
            int kk  = (LO & 127) >> 1;           // bf16 element offset
            int ra = m0 + row; if (ra > mClamp) ra = mClamp;
            gload16(A + (size_t)ra * K + k0 + kk, (char*)As + LO);
            gload16(B + (size_t)(n0 + row) * K + k0 + kk, (char*)Bs + LO);
        }
        asm volatile("s_waitcnt vmcnt(0)" ::: "memory");
        __syncthreads();
#pragma unroll
        for (int kk = 0; kk < 2; ++kk) {
            bf16x8 a[4], bb[4];
#pragma unroll
            for (int f = 0; f < 4; ++f) {
                a[f]  = *(const bf16x8*)&As[(wr*64 + f*16 + (lane & 15))*64 + kk*32 + (lane >> 4)*8];
                bb[f] = *(const bf16x8*)&Bs[(wc*64 + f*16 + (lane & 15))*64 + kk*32 + (lane >> 4)*8];
            }
#pragma unroll
            for (int fr = 0; fr < 4; ++fr)
#pragma unroll
                for (int fc = 0; fc < 4; ++fc)
                    acc[fr][fc] = __builtin_amdgcn_mfma_f32_16x16x32_bf16(a[fr], bb[fc], acc[fr][fc], 0, 0, 0);
        }
        __syncthreads();
    }
}

// ---------------------------------------------------------------------------
// feat (b,K,H,W) fp32 -> A (rows = (b,pooled,sub), K) bf16 transpose.
// 64 rows x 64 k per block via LDS.
// ---------------------------------------------------------------------------
__global__ __launch_bounds__(256)
void feat_transpose(const float* __restrict__ x, unsigned short* __restrict__ A,
                    int K, int H, int W, int b0)
{
    __shared__ __align__(16) unsigned short T[64 * 72];
    const int t = threadIdx.x;
    const int m0 = blockIdx.x << 6, k0 = blockIdx.y << 6;
    const int HW = H * W, W2 = W >> 1;
    const int p = t & 63;
    const int graw = b0 * HW + m0 + p;
    const int b = graw / HW;
    const int rem = graw - b * HW;
    const int pooled = rem >> 2, sub = rem & 3;
    const int pi = pooled / W2, pj = pooled - pi * W2;
    const int i = pi * 2 + (sub >> 1), j = pj * 2 + (sub & 1);
    const float* src = x + (size_t)b * K * HW + (size_t)i * W + j;
    const int kw = t >> 6;
#pragma unroll
    for (int it = 0; it < 16; ++it) {
        int k_l = it * 4 + kw;
        T[p * 72 + k_l] = f2bf(src[(size_t)(k0 + k_l) * HW]);
    }
    __syncthreads();
    const int row = t >> 2, part = t & 3;
    u16x8 v0 = *(const u16x8*)&T[row * 72 + part * 16];
    u16x8 v1 = *(const u16x8*)&T[row * 72 + part * 16 + 8];
    unsigned short* dst = A + (size_t)(m0 + row) * K + k0 + part * 16;
    *(u16x8*)dst = v0;
    *(u16x8*)(dst + 8) = v1;
}

// fp32 (R,C) -> bf16 (C,R) transpose (weights)
__global__ __launch_bounds__(256)
void wt_transpose(const float* __restrict__ in, unsigned short* __restrict__ outT,
                  int R, int Ccols)
{
    __shared__ float T[32][33];
    const int tx = threadIdx.x & 31, ty = threadIdx.x >> 5;
    const int c0 = blockIdx.x << 5, r0 = blockIdx.y << 5;
#pragma unroll
    for (int i = 0; i < 4; ++i)
        T[ty + i * 8][tx] = in[(size_t)(r0 + ty + i * 8) * Ccols + c0 + tx];
    __syncthreads();
#pragma unroll
    for (int i = 0; i < 4; ++i)
        outT[(size_t)(c0 + ty + i * 8) * R + r0 + tx] = f2bf(T[tx][ty + i * 8]);
}

// fp32 -> bf16 plain convert (dw weights)
__global__ __launch_bounds__(256)
void cvt_bf16(const float* __restrict__ in, unsigned short* __restrict__ out, int n)
{
    int idx = (blockIdx.x * 256 + threadIdx.x) * 8;
    if (idx < n) {
        float4 a = *(const float4*)(in + idx);
        float4 c = *(const float4*)(in + idx + 4);
        u16x8 r;
        r[0] = f2bf(a.x); r[1] = f2bf(a.y); r[2] = f2bf(a.z); r[3] = f2bf(a.w);
        r[4] = f2bf(c.x); r[5] = f2bf(c.y); r[6] = f2bf(c.z); r[7] = f2bf(c.w);
        *(u16x8*)(out + idx) = r;
    }
}

// BN scale/shift precompute (one scale per launch)
__global__ void prep_scsh(const float* __restrict__ g, const float* __restrict__ bb,
                          const float* __restrict__ mm, const float* __restrict__ vv,
                          const float* __restrict__ db, float* __restrict__ out)
{
    int o = threadIdx.x;
    float sc = g[o] * rsqrtf(vv[o] + 1e-5f);
    out[o] = sc;
    out[256 + o] = (db[o] - mm[o]) * sc + bb[o];
}

// ---------------------------------------------------------------------------
// conv1x1 GEMM + BN + ReLU + pool epilogue -> h0 bf16 node-major
// ---------------------------------------------------------------------------
template<int PP>
__global__ __launch_bounds__(256)
void conv_gemm(const unsigned short* __restrict__ A, const unsigned short* __restrict__ Bw,
               const float* __restrict__ scsh, unsigned short* __restrict__ h0out,
               int K, int qBase, int noff, int mRows)
{
    __shared__ __align__(16) unsigned short As[8192], Bs[8192];
    const int m0 = blockIdx.y << 7, n0 = blockIdx.x << 7;
    f32x4 acc[4][4];
#pragma unroll
    for (int fr = 0; fr < 4; ++fr)
#pragma unroll
        for (int fc = 0; fc < 4; ++fc) acc[fr][fc] = (f32x4){0.f, 0.f, 0.f, 0.f};

    gemm_core(A, Bw, K, m0, n0, mRows - 1, As, Bs, acc);

    const int lane = threadIdx.x & 63, w = threadIdx.x >> 6;
    const int wr = w >> 1, wc = w & 1;
#pragma unroll
    for (int fc = 0; fc < 4; ++fc) {
        const int o = n0 + wc * 64 + fc * 16 + (lane & 15);
        const float sc = scsh[o], sh = scsh[256 + o];
#pragma unroll
        for (int fr = 0; fr < 4; ++fr) {
            int q = qBase + ((m0 + wr * 64 + fr * 16) >> 2) + (lane >> 4);
            int bi = q / PP;
            int node = noff + (q - bi * PP);
            float s = 0.f;
#pragma unroll
            for (int r = 0; r < 4; ++r)
                s += fmaxf(acc[fr][fc][r] * sc + sh, 0.f);
            h0out[((size_t)(bi * NODES + node)) * 256 + o] = f2bf(s * 0.25f);
        }
    }
}

// ---------------------------------------------------------------------------
// GNN mean-aggregation (analytic neighbor lists), bf16 in/out
// ---------------------------------------------------------------------------
__global__ __launch_bounds__(256)
void gnn_gather(const unsigned short* __restrict__ h, unsigned short* __restrict__ agg, int hier)
{
    const int t = threadIdx.x;
    const int pid = (blockIdx.x << 3) + (t >> 5);
    const int c0 = (t & 31) << 3;
    const int b = pid / NODES;
    const int n = pid - b * NODES;
    const size_t hb = (size_t)b * NODES * 256 + c0;

    int gw, off;
    if (n < 1600)      { gw = 40; off = 0; }
    else if (n < 2000) { gw = 20; off = 1600; }
    else               { gw = 10; off = 2000; }
    const int loc = n - off;
    const int i = loc / gw;
    const int j = loc - i * gw;

    float s[8] = {0, 0, 0, 0, 0, 0, 0, 0};
    int cnt = 0;
#define ACC1(node) { u16x8 v = *(const u16x8*)(h + hb + (size_t)(node) * 256); \
    _Pragma("unroll") for (int e = 0; e < 8; ++e) s[e] += bf2f(v[e]); ++cnt; }

    if (!hier) {
#pragma unroll
        for (int di = -1; di <= 1; ++di)
#pragma unroll
            for (int dj = -1; dj <= 1; ++dj) {
                int ii = i + di, jj = j + dj;
                if (ii >= 0 && ii < gw && jj >= 0 && jj < gw) ACC1(off + ii * gw + jj);
            }
    } else {
        ACC1(n);
        if (off == 0) {
            ACC1(1600 + (i >> 1) * 20 + (j >> 1));
        } else if (off == 1600) {
            ACC1(2000 + (i >> 1) * 10 + (j >> 1));
#pragma unroll
            for (int di = 0; di < 2; ++di)
#pragma unroll
                for (int dj = 0; dj < 2; ++dj)
                    ACC1(((i << 1) + di) * 40 + ((j << 1) + dj));
        } else {
#pragma unroll
            for (int di = 0; di < 2; ++di)
#pragma unroll
                for (int dj = 0; dj < 2; ++dj)
                    ACC1(1600 + ((i << 1) + di) * 20 + ((j << 1) + dj));
        }
    }
#undef ACC1
    const float inv = 1.0f / (float)cnt;
    u16x8 r;
#pragma unroll
    for (int e = 0; e < 8; ++e) r[e] = f2bf(s[e] * inv);
    *(u16x8*)(agg + (size_t)pid * 256 + c0) = r;
}

// ---------------------------------------------------------------------------
// GNN dense: out = relu(A x gW + bias), bf16 out
// ---------------------------------------------------------------------------
__global__ __launch_bounds__(256)
void gnn_gemm(const unsigned short* __restrict__ A, const unsigned short* __restrict__ BT,
              const float* __restrict__ bias, unsigned short* __restrict__ out, int M)
{
    __shared__ __align__(16) unsigned short As[8192], Bs[8192];
    const int m0 = blockIdx.y << 7, n0 = blockIdx.x << 7;
    f32x4 acc[4][4];
#pragma unroll
    for (int fr = 0; fr < 4; ++fr)
#pragma unroll
        for (int fc = 0; fc < 4; ++fc) acc[fr][fc] = (f32x4){0.f, 0.f, 0.f, 0.f};

    gemm_core(A, BT, 256, m0, n0, M - 1, As, Bs, acc);

    const int lane = threadIdx.x & 63, w = threadIdx.x >> 6;
    const int wr = w >> 1, wc = w & 1;
#pragma unroll
    for (int fc = 0; fc < 4; ++fc) {
        const int d = n0 + wc * 64 + fc * 16 + (lane & 15);
        const float bv = bias[d];
#pragma unroll
        for (int fr = 0; fr < 4; ++fr) {
            int rb = m0 + wr * 64 + fr * 16 + (lane >> 4) * 4;
#pragma unroll
            for (int r = 0; r < 4; ++r) {
                int row = rb + r;
                if (row < M)
                    out[(size_t)row * 256 + d] = f2bf(fmaxf(acc[fr][fc][r] + bv, 0.f));
            }
        }
    }
}

// ---------------------------------------------------------------------------
// convT A-matrix build: a[m][c] = h0 + h6 (+ h6[parent]), bf16
// ---------------------------------------------------------------------------
__global__ __launch_bounds__(256)
void a_build(const unsigned short* __restrict__ h0, const unsigned short* __restrict__ h6,
             unsigned short* __restrict__ Ao, int P, int H2, int noff,
             int pbase, int pw, int haspar)
{
    const int gid = blockIdx.x * 256 + threadIdx.x;
    const int m = gid >> 5, c0 = (gid & 31) << 3;
    const int b = m / P, pix = m - b * P;
    const size_t src = ((size_t)(b * NODES + noff + pix)) * 256 + c0;
    u16x8 x0 = *(const u16x8*)(h0 + src);
    u16x8 x6 = *(const u16x8*)(h6 + src);
    float v[8];
#pragma unroll
    for (int e = 0; e < 8; ++e) v[e] = bf2f(x0[e]) + bf2f(x6[e]);
    if (haspar) {
        int ii = pix / H2, jj = pix - ii * H2;
        size_t sp = ((size_t)(b * NODES + pbase + (ii >> 1) * pw + (jj >> 1))) * 256 + c0;
        u16x8 xp = *(const u16x8*)(h6 + sp);
#pragma unroll
        for (int e = 0; e < 8; ++e) v[e] += bf2f(xp[e]);
    }
    u16x8 r;
#pragma unroll
    for (int e = 0; e < 8; ++e) r[e] = f2bf(v[e]);
    *(u16x8*)(Ao + (size_t)m * 256 + c0) = r;
}

// ---------------------------------------------------------------------------
// convT2x2 GEMM + bias + residual scatter epilogue (fp32 out)
// ---------------------------------------------------------------------------
template<int P, int H2>
__global__ __launch_bounds__(256)
void convt_gemm(const unsigned short* __restrict__ Ao, const unsigned short* __restrict__ BT,
                const float* __restrict__ tb, const float* __restrict__ feat,
                float* __restrict__ out, int Cout, int M)
{
    __shared__ __align__(16) unsigned short As[8192], Bs[8192];
    const int m0 = blockIdx.y << 7, n0 = blockIdx.x << 7;
    f32x4 acc[4][4];
#pragma unroll
    for (int fr = 0; fr < 4; ++fr)
#pragma unroll
        for (int fc = 0; fc < 4; ++fc) acc[fr][fc] = (f32x4){0.f, 0.f, 0.f, 0.f};

    gemm_core(Ao, BT, 256, m0, n0, M - 1, As, Bs, acc);

    const int lane = threadIdx.x & 63, w = threadIdx.x >> 6;
    const int wr = w >> 1, wc = w & 1;
    const int H = H2 * 2;
#pragma unroll
    for (int fc = 0; fc < 4; ++fc) {
        const int col = n0 + wc * 64 + fc * 16 + (lane & 15);
        const int o = col >> 2, s = col & 3;
        const int di = s >> 1, dj = s & 1;
        const float tbo = tb[o];
#pragma unroll
        for (int fr = 0; fr < 4; ++fr) {
            int rb = m0 + wr * 64 + fr * 16 + (lane >> 4) * 4;
#pragma unroll
            for (int r = 0; r < 4; ++r) {
                int row = rb + r;
                if (row < M) {
                    int b = row / P, pix = row - b * P;
                    int ii = pix / H2, jj = pix - ii * H2;
                    size_t a = (((size_t)(b * Cout + o)) * H + (ii * 2 + di)) * H + (jj * 2 + dj);
                    out[a] = acc[fr][fc][r] + tbo + feat[a];
                }
            }
        }
    }
}

// ---------------------------------------------------------------------------
extern "C" void kernel_launch(void* const* d_in, const int* in_sizes, int n_in,
                              void* d_out, int out_size, void* d_ws, size_t ws_size,
                              hipStream_t stream)
{
    const float* feats[3] = { (const float*)d_in[1], (const float*)d_in[2], (const float*)d_in[3] };
    const float* dw[3]  = { (const float*)d_in[4],  (const float*)d_in[10], (const float*)d_in[16] };
    const float* dbv[3] = { (const float*)d_in[5],  (const float*)d_in[11], (const float*)d_in[17] };
    const float* gv[3]  = { (const float*)d_in[6],  (const float*)d_in[12], (const float*)d_in[18] };
    const float* bv[3]  = { (const float*)d_in[7],  (const float*)d_in[13], (const float*)d_in[19] };
    const float* mv[3]  = { (const float*)d_in[8],  (const float*)d_in[14], (const float*)d_in[20] };
    const float* vv[3]  = { (const float*)d_in[9],  (const float*)d_in[15], (const float*)d_in[21] };
    const float* gW[6]; const float* gb[6];
    for (int l = 0; l < 6; ++l) {
        gW[l] = (const float*)d_in[22 + 2 * l];
        gb[l] = (const float*)d_in[23 + 2 * l];
    }
    const float* tW[3] = { (const float*)d_in[34], (const float*)d_in[36], (const float*)d_in[38] };
    const float* tb[3] = { (const float*)d_in[35], (const float*)d_in[37], (const float*)d_in[39] };

    // ---- workspace layout (bytes) ----
    size_t off = 0;
    auto alloc = [&](size_t bytes) { size_t r = off; off = (off + bytes + 511) & ~(size_t)511; return r; };
    unsigned short* h0b  = (unsigned short*)((char*)d_ws + alloc(16800ULL * 256 * 2));
    unsigned short* hA   = (unsigned short*)((char*)d_ws + alloc(16800ULL * 256 * 2));
    unsigned short* hB   = (unsigned short*)((char*)d_ws + alloc(16800ULL * 256 * 2));
    unsigned short* dwb  = (unsigned short*)((char*)d_ws + alloc(917504ULL * 2));
    unsigned short* gWTb = (unsigned short*)((char*)d_ws + alloc(6ULL * 65536 * 2));
    float*          scshb= (float*)((char*)d_ws + alloc(3ULL * 512 * 4));
    const size_t fixedBytes = off;
    const size_t convtNeed = ((16800ULL * 256 * 2 + 511) & ~(size_t)511) + 3670016ULL * 2;
    const bool big = ws_size >= fixedBytes + 52428800ULL + 1024;
    char* BIG = (char*)d_ws + off;
    unsigned short* Afeat = (unsigned short*)BIG;     // conv phase
    unsigned short* aggb  = (unsigned short*)BIG;     // GNN phase
    unsigned short* Aconvt= (unsigned short*)BIG;     // convt phase
    unsigned short* tWTb  = (unsigned short*)(BIG + ((16800ULL * 256 * 2 + 511) & ~(size_t)511));
    (void)convtNeed;

    // ---- feat0 passthrough ----
    hipMemcpyAsync(d_out, d_in[0], 52428800ULL * 4, hipMemcpyDeviceToDevice, stream);

    // ---- weight conversions ----
    const int Ks[3] = {512, 1024, 2048};
    size_t dwoff[3] = {0, 131072, 393216};
    for (int s = 0; s < 3; ++s) {
        int n = 256 * Ks[s];
        cvt_bf16<<<dim3((n / 8 + 255) / 256), dim3(256), 0, stream>>>(dw[s], dwb + dwoff[s], n);
        prep_scsh<<<dim3(1), dim3(256), 0, stream>>>(gv[s], bv[s], mv[s], vv[s], dbv[s], scshb + s * 512);
    }
    for (int l = 0; l < 6; ++l)
        wt_transpose<<<dim3(8, 8), dim3(256), 0, stream>>>(gW[l], gWTb + l * 65536, 256, 256);

    // ---- conv1x1 + BN + ReLU + pool  (chunked by batch if ws is small) ----
    const int Hs[3] = {80, 40, 20};
    const int PPs[3] = {1600, 400, 100};
    const int noffs[3] = {0, 1600, 2000};
    const int nch[3] = { big ? 1 : 4, big ? 1 : 2, 1 };
    for (int s = 0; s < 3; ++s) {
        const int H = Hs[s], HW = H * H, K = Ks[s];
        const int bPer = 8 / nch[s];
        const int rows = bPer * HW;
        for (int c = 0; c < nch[s]; ++c) {
            int b0 = c * bPer;
            feat_transpose<<<dim3(rows / 64, K / 64), dim3(256), 0, stream>>>(
                feats[s], Afeat, K, H, H, b0);
            dim3 grid(2, rows / 128);
            if (s == 0)
                conv_gemm<1600><<<grid, dim3(256), 0, stream>>>(Afeat, dwb + dwoff[s], scshb + s * 512, h0b, K, b0 * PPs[s], noffs[s], rows);
            else if (s == 1)
                conv_gemm<400><<<grid, dim3(256), 0, stream>>>(Afeat, dwb + dwoff[s], scshb + s * 512, h0b, K, b0 * PPs[s], noffs[s], rows);
            else
                conv_gemm<100><<<grid, dim3(256), 0, stream>>>(Afeat, dwb + dwoff[s], scshb + s * 512, h0b, K, b0 * PPs[s], noffs[s], rows);
        }
    }

    // ---- 6 GNN layers ----
    const int types[6] = {0, 0, 1, 1, 0, 0};
    const unsigned short* hin = h0b;
    unsigned short* houts[6] = {hA, hB, hA, hB, hA, hB};
    for (int l = 0; l < 6; ++l) {
        gnn_gather<<<dim3(NODES), dim3(256), 0, stream>>>(hin, aggb, types[l]);
        gnn_gemm<<<dim3(2, 132), dim3(256), 0, stream>>>(aggb, gWTb + l * 65536, gb[l], houts[l], 16800);
        hin = houts[l];
    }
    unsigned short* h6 = hB;

    // ---- convT phase ----
    // A matrices: rows s1 @0 (12800), s2 @12800 (3200), s3 @16000 (800)
    a_build<<<dim3(1600), dim3(256), 0, stream>>>(h0b, h6, Aconvt,            1600, 40, 0,    1600, 20, 1);
    a_build<<<dim3(400),  dim3(256), 0, stream>>>(h0b, h6, Aconvt + 12800ULL * 256, 400, 20, 1600, 2000, 10, 1);
    a_build<<<dim3(100),  dim3(256), 0, stream>>>(h0b, h6, Aconvt + 16000ULL * 256, 100, 10, 2000, 0, 0, 0);

    const int Couts[3] = {512, 1024, 2048};
    size_t tWToff[3] = {0, 524288, 1572864};
    for (int s = 0; s < 3; ++s) {
        int Ncol = Couts[s] * 4;
        wt_transpose<<<dim3(Ncol / 32, 8), dim3(256), 0, stream>>>(tW[s], tWTb + tWToff[s], 256, Ncol);
    }

    float* out1 = (float*)d_out + 52428800;
    float* out2 = out1 + 26214400;
    float* out3 = out2 + 13107200;
    convt_gemm<1600, 40><<<dim3(16, 100), dim3(256), 0, stream>>>(
        Aconvt,                tWTb + tWToff[0], tb[0], feats[0], out1, 512, 12800);
    convt_gemm<400, 20><<<dim3(32, 25), dim3(256), 0, stream>>>(
        Aconvt + 12800ULL * 256, tWTb + tWToff[1], tb[1], feats[1], out2, 1024, 3200);
    convt_gemm<100, 10><<<dim3(64, 7), dim3(256), 0, stream>>>(
        Aconvt + 16000ULL * 256, tWTb + tWToff[2], tb[2], feats[2], out3, 2048, 800);
}

// Round 3
// 573.328 us; speedup vs baseline: 3.4332x; 1.2806x over previous
//
#include <hip/hip_runtime.h>
#include <cstdint>

#define NODES 2100

typedef __attribute__((ext_vector_type(8))) __bf16 bf16x8;
typedef __attribute__((ext_vector_type(4))) float f32x4;
typedef __attribute__((ext_vector_type(8))) unsigned short u16x8;

__device__ inline float bf2f(unsigned short s) { return __uint_as_float(((unsigned)s) << 16); }
__device__ inline unsigned short f2bf(float f) {
    unsigned u = __float_as_uint(f);
    u += 0x7fff + ((u >> 16) & 1);          // RNE
    return (unsigned short)(u >> 16);
}
__device__ inline void gload16(const unsigned short* g, void* lds) {
    __builtin_amdgcn_global_load_lds(
        (const __attribute__((address_space(1))) void*)g,
        (__attribute__((address_space(3))) void*)lds, 16, 0, 0);
}

// ---------------------------------------------------------------------------
// Shared MFMA GEMM core, 128x128 tile, BK=64, 256 thr = 4 waves (2x2).
// LDS tiles are XOR-swizzled (byte ^= (row&7)<<4) to kill the 16-way bank
// conflict of 128-B-stride rows; global_load_lds writes linearly, so the
// SOURCE k-offset is pre-swizzled (same involution) and reads apply the XOR.
// ---------------------------------------------------------------------------
__device__ __attribute__((always_inline)) inline
void gemm_core(const unsigned short* __restrict__ A, const unsigned short* __restrict__ B,
               int K, int m0, int n0, int mClamp, int nClamp,
               unsigned short* As, unsigned short* Bs, f32x4 acc[4][4])
{
    const int t = threadIdx.x, lane = t & 63, w = t >> 6;
    const int wr = w >> 1, wc = w & 1;
    const int sx = (lane & 7) << 4;                  // read-side XOR (bytes)
    for (int k0 = 0; k0 < K; k0 += 64) {
#pragma unroll
        for (int i = 0; i < 4; ++i) {
            int LO  = ((i << 8) + t) << 4;           // physical byte offset
            int row = LO >> 7;
            int kb  = (LO & 127) ^ ((row & 7) << 4); // pre-swizzled source k-byte
            int ke  = kb >> 1;
            int ra = m0 + row; if (ra > mClamp) ra = mClamp;
            int rb = n0 + row; if (rb > nClamp) rb = nClamp;
            gload16(A + (size_t)ra * K + k0 + ke, (char*)As + LO);
            gload16(B + (size_t)rb * K + k0 + ke, (char*)Bs + LO);
        }
        asm volatile("s_waitcnt vmcnt(0)" ::: "memory");
        __syncthreads();
#pragma unroll
        for (int kk = 0; kk < 2; ++kk) {
            bf16x8 a[4], bb[4];
#pragma unroll
            for (int f = 0; f < 4; ++f) {
                int pa = (((wr * 64 + f * 16 + (lane & 15)) << 7) + kk * 64 + ((lane >> 4) << 4)) ^ sx;
                int pb = (((wc * 64 + f * 16 + (lane & 15)) << 7) + kk * 64 + ((lane >> 4) << 4)) ^ sx;
                a[f]  = *(const bf16x8*)((const char*)As + pa);
                bb[f] = *(const bf16x8*)((const char*)Bs + pb);
            }
#pragma unroll
            for (int fr = 0; fr < 4; ++fr)
#pragma unroll
                for (int fc = 0; fc < 4; ++fc)
                    acc[fr][fc] = __builtin_amdgcn_mfma_f32_16x16x32_bf16(a[fr], bb[fc], acc[fr][fc], 0, 0, 0);
        }
        __syncthreads();
    }
}

// ---------------------------------------------------------------------------
// feat (b,K,H,W) fp32 -> A (rows = (b,pooled,sub), K) bf16 transpose.
// ---------------------------------------------------------------------------
__global__ __launch_bounds__(256)
void feat_transpose(const float* __restrict__ x, unsigned short* __restrict__ A,
                    int K, int H, int W, int b0)
{
    __shared__ __align__(16) unsigned short T[64 * 72];
    const int t = threadIdx.x;
    const int m0 = blockIdx.x << 6, k0 = blockIdx.y << 6;
    const int HW = H * W, W2 = W >> 1;
    const int p = t & 63;
    const int graw = b0 * HW + m0 + p;
    const int b = graw / HW;
    const int rem = graw - b * HW;
    const int pooled = rem >> 2, sub = rem & 3;
    const int pi = pooled / W2, pj = pooled - pi * W2;
    const int i = pi * 2 + (sub >> 1), j = pj * 2 + (sub & 1);
    const float* src = x + (size_t)b * K * HW + (size_t)i * W + j;
    const int kw = t >> 6;
#pragma unroll
    for (int it = 0; it < 16; ++it) {
        int k_l = it * 4 + kw;
        T[p * 72 + k_l] = f2bf(src[(size_t)(k0 + k_l) * HW]);
    }
    __syncthreads();
    const int row = t >> 2, part = t & 3;
    u16x8 v0 = *(const u16x8*)&T[row * 72 + part * 16];
    u16x8 v1 = *(const u16x8*)&T[row * 72 + part * 16 + 8];
    unsigned short* dst = A + (size_t)(m0 + row) * K + k0 + part * 16;
    *(u16x8*)dst = v0;
    *(u16x8*)(dst + 8) = v1;
}

// ---------------------------------------------------------------------------
// mega-prep: all weight conversions/transposes + BN scale/shift in ONE launch
// blocks [0,448) dw cvt | [448,832) gW T | [832,4416) tW T | 4416 scsh
// ---------------------------------------------------------------------------
struct PrepArgs {
    const float *dw0, *dw1, *dw2;
    const float *gw0, *gw1, *gw2, *gw3, *gw4, *gw5;
    const float *tw0, *tw1, *tw2;
    const float *g0, *g1, *g2, *b0, *b1, *b2, *m0, *m1, *m2, *v0, *v1, *v2, *db0, *db1, *db2;
    unsigned short *dwb, *gWTb, *tWTb;
    float *scshb;
};

__device__ inline void transpose32(const float* __restrict__ in, unsigned short* __restrict__ outT,
                                   int Ccols, int c0, int r0)
{
    __shared__ float T[32][33];
    const int tx = threadIdx.x & 31, ty = threadIdx.x >> 5;
#pragma unroll
    for (int i = 0; i < 4; ++i)
        T[ty + i * 8][tx] = in[(size_t)(r0 + ty + i * 8) * Ccols + c0 + tx];
    __syncthreads();
#pragma unroll
    for (int i = 0; i < 4; ++i)
        outT[(size_t)(c0 + ty + i * 8) * 256 + r0 + tx] = f2bf(T[tx][ty + i * 8]);
}

__global__ __launch_bounds__(256)
void mega_prep(PrepArgs a)
{
    const int bid = blockIdx.x, t = threadIdx.x;
    if (bid < 448) {                           // dw convert (concatenated)
        int idx = (bid * 256 + t) * 8;
        const float* src;
        int loc;
        if (idx < 131072)      { src = a.dw0; loc = idx; }
        else if (idx < 393216) { src = a.dw1; loc = idx - 131072; }
        else                   { src = a.dw2; loc = idx - 393216; }
        float4 x = *(const float4*)(src + loc);
        float4 y = *(const float4*)(src + loc + 4);
        u16x8 r;
        r[0] = f2bf(x.x); r[1] = f2bf(x.y); r[2] = f2bf(x.z); r[3] = f2bf(x.w);
        r[4] = f2bf(y.x); r[5] = f2bf(y.y); r[6] = f2bf(y.z); r[7] = f2bf(y.w);
        *(u16x8*)(a.dwb + idx) = r;
    } else if (bid < 832) {                    // gW transpose: 6 x (8x8 blocks)
        int gid = bid - 448;
        int l = gid >> 6, sb = gid & 63;
        const float* gw[6] = {a.gw0, a.gw1, a.gw2, a.gw3, a.gw4, a.gw5};
        transpose32(gw[l], a.gWTb + (size_t)l * 65536, 256, (sb & 7) << 5, (sb >> 3) << 5);
    } else if (bid < 4416) {                   // tW transpose
        int gid = bid - 832;
        const float* tw; unsigned short* dst; int ncx, loc;
        if (gid < 512)       { tw = a.tw0; dst = a.tWTb;           ncx = 64;  loc = gid; }
        else if (gid < 1536) { tw = a.tw1; dst = a.tWTb + 524288;  ncx = 128; loc = gid - 512; }
        else                 { tw = a.tw2; dst = a.tWTb + 1572864; ncx = 256; loc = gid - 1536; }
        int cx = loc % ncx, ry = loc / ncx;
        transpose32(tw, dst, ncx * 32, cx << 5, ry << 5);
    } else {                                   // BN scale/shift
        const float* g[3]  = {a.g0, a.g1, a.g2};
        const float* b[3]  = {a.b0, a.b1, a.b2};
        const float* m[3]  = {a.m0, a.m1, a.m2};
        const float* v[3]  = {a.v0, a.v1, a.v2};
        const float* db[3] = {a.db0, a.db1, a.db2};
        for (int s = 0; s < 3; ++s) {
            float sc = g[s][t] * rsqrtf(v[s][t] + 1e-5f);
            a.scshb[s * 512 + t] = sc;
            a.scshb[s * 512 + 256 + t] = (db[s][t] - m[s][t]) * sc + b[s][t];
        }
    }
}

// ---------------------------------------------------------------------------
// conv1x1 GEMM + BN + ReLU + pool epilogue -> h0 bf16 node-major
// ---------------------------------------------------------------------------
template<int PP>
__global__ __launch_bounds__(256)
void conv_gemm(const unsigned short* __restrict__ A, const unsigned short* __restrict__ Bw,
               const float* __restrict__ scsh, unsigned short* __restrict__ h0out,
               int K, int qBase, int noff, int mRows)
{
    __shared__ __align__(16) unsigned short As[8192], Bs[8192];
    const int m0 = blockIdx.y << 7, n0 = blockIdx.x << 7;
    f32x4 acc[4][4];
#pragma unroll
    for (int fr = 0; fr < 4; ++fr)
#pragma unroll
        for (int fc = 0; fc < 4; ++fc) acc[fr][fc] = (f32x4){0.f, 0.f, 0.f, 0.f};

    gemm_core(A, Bw, K, m0, n0, mRows - 1, 255, As, Bs, acc);

    const int lane = threadIdx.x & 63, w = threadIdx.x >> 6;
    const int wr = w >> 1, wc = w & 1;
#pragma unroll
    for (int fc = 0; fc < 4; ++fc) {
        const int o = n0 + wc * 64 + fc * 16 + (lane & 15);
        const float sc = scsh[o], sh = scsh[256 + o];
#pragma unroll
        for (int fr = 0; fr < 4; ++fr) {
            int q = qBase + ((m0 + wr * 64 + fr * 16) >> 2) + (lane >> 4);
            int bi = q / PP;
            int node = noff + (q - bi * PP);
            float s = 0.f;
#pragma unroll
            for (int r = 0; r < 4; ++r)
                s += fmaxf(acc[fr][fc][r] * sc + sh, 0.f);
            h0out[((size_t)(bi * NODES + node)) * 256 + o] = f2bf(s * 0.25f);
        }
    }
}

// ---------------------------------------------------------------------------
// Fused GNN layer: gather (analytic neighbor lists) builds the A-tile
// in-kernel, then MFMA with the weight matrix.  BM=64 rows, BN=256 cols,
// 4 waves each owning a 64x64 C sub-tile.  out = relu(mean_nbr(h) @ W + b).
// ---------------------------------------------------------------------------
__global__ __launch_bounds__(256)
void gnn_fused(const unsigned short* __restrict__ h, const unsigned short* __restrict__ BT,
               const float* __restrict__ bias, unsigned short* __restrict__ out, int hier)
{
    __shared__ __align__(16) unsigned short As[64 * 72];     // padded rows (9216 B)
    __shared__ __align__(16) unsigned short Bs[256 * 64];    // swizzled (32 KB)
    const int t = threadIdx.x, lane = t & 63, w = t >> 6;
    const int r0 = blockIdx.x << 6;
    const int myrow = t >> 2, q = t & 3;
    int grow = r0 + myrow; if (grow > 16799) grow = 16799;
    const int b = grow / NODES;
    const int n = grow - b * NODES;

    int gw, off;
    if (n < 1600)      { gw = 40; off = 0; }
    else if (n < 2000) { gw = 20; off = 1600; }
    else               { gw = 10; off = 2000; }
    const int li = (n - off) / gw;
    const int lj = (n - off) - li * gw;
    int nbr[9]; int cnt = 0;
    if (!hier) {
#pragma unroll
        for (int di = -1; di <= 1; ++di)
#pragma unroll
            for (int dj = -1; dj <= 1; ++dj) {
                int ii = li + di, jj = lj + dj;
                if (ii >= 0 && ii < gw && jj >= 0 && jj < gw) nbr[cnt++] = off + ii * gw + jj;
            }
    } else {
        nbr[cnt++] = n;
        if (off == 0) {
            nbr[cnt++] = 1600 + (li >> 1) * 20 + (lj >> 1);
        } else if (off == 1600) {
            nbr[cnt++] = 2000 + (li >> 1) * 10 + (lj >> 1);
#pragma unroll
            for (int di = 0; di < 2; ++di)
#pragma unroll
                for (int dj = 0; dj < 2; ++dj)
                    nbr[cnt++] = ((li << 1) + di) * 40 + ((lj << 1) + dj);
        } else {
#pragma unroll
            for (int di = 0; di < 2; ++di)
#pragma unroll
                for (int dj = 0; dj < 2; ++dj)
                    nbr[cnt++] = 1600 + ((li << 1) + di) * 20 + ((lj << 1) + dj);
        }
    }
    int nboff[9];
#pragma unroll
    for (int e = 0; e < 9; ++e)
        nboff[e] = (b * NODES + nbr[e < cnt ? e : 0]) * 256 + q * 16;
    const float inv = 1.0f / (float)cnt;
    const int sx = (lane & 7) << 4;

    f32x4 acc[4][4];
#pragma unroll
    for (int fr = 0; fr < 4; ++fr)
#pragma unroll
        for (int fc = 0; fc < 4; ++fc) acc[fr][fc] = (f32x4){0.f, 0.f, 0.f, 0.f};

    for (int k0 = 0; k0 < 256; k0 += 64) {
        // B stage (weights, swizzled source)
#pragma unroll
        for (int i = 0; i < 8; ++i) {
            int LO = ((i << 8) + t) << 4;
            int row = LO >> 7;
            int kb = (LO & 127) ^ ((row & 7) << 4);
            gload16(BT + (size_t)row * 256 + k0 + (kb >> 1), (char*)Bs + LO);
        }
        // A gather: mean of neighbor rows, 16 k per thread
        float s[16];
#pragma unroll
        for (int j = 0; j < 16; ++j) s[j] = 0.f;
        for (int e = 0; e < cnt; ++e) {
            const unsigned short* p = h + nboff[e] + k0;
            u16x8 v0 = *(const u16x8*)p;
            u16x8 v1 = *(const u16x8*)(p + 8);
#pragma unroll
            for (int j = 0; j < 8; ++j) { s[j] += bf2f(v0[j]); s[8 + j] += bf2f(v1[j]); }
        }
        u16x8 o0, o1;
#pragma unroll
        for (int j = 0; j < 8; ++j) { o0[j] = f2bf(s[j] * inv); o1[j] = f2bf(s[8 + j] * inv); }
        *(u16x8*)&As[myrow * 72 + q * 16] = o0;
        *(u16x8*)&As[myrow * 72 + q * 16 + 8] = o1;

        asm volatile("s_waitcnt vmcnt(0)" ::: "memory");
        __syncthreads();
#pragma unroll
        for (int kk = 0; kk < 2; ++kk) {
            bf16x8 a[4], bb[4];
#pragma unroll
            for (int f = 0; f < 4; ++f) {
                a[f] = *(const bf16x8*)&As[(f * 16 + (lane & 15)) * 72 + kk * 32 + (lane >> 4) * 8];
                int pb = (((w * 64 + f * 16 + (lane & 15)) << 7) + kk * 64 + ((lane >> 4) << 4)) ^ sx;
                bb[f] = *(const bf16x8*)((const char*)Bs + pb);
            }
#pragma unroll
            for (int fr = 0; fr < 4; ++fr)
#pragma unroll
                for (int fc = 0; fc < 4; ++fc)
                    acc[fr][fc] = __builtin_amdgcn_mfma_f32_16x16x32_bf16(a[fr], bb[fc], acc[fr][fc], 0, 0, 0);
        }
        __syncthreads();
    }

#pragma unroll
    for (int fc = 0; fc < 4; ++fc) {
        const int d = w * 64 + fc * 16 + (lane & 15);
        const float bv = bias[d];
#pragma unroll
        for (int fr = 0; fr < 4; ++fr) {
            int rb = r0 + fr * 16 + (lane >> 4) * 4;
#pragma unroll
            for (int r = 0; r < 4; ++r) {
                int row = rb + r;
                if (row < 16800)
                    out[(size_t)row * 256 + d] = f2bf(fmaxf(acc[fr][fc][r] + bv, 0.f));
            }
        }
    }
}

// ---------------------------------------------------------------------------
// convT A-matrix build: a[m][c] = h0 + h6 (+ h6[parent]), bf16.  ONE launch.
// ---------------------------------------------------------------------------
__global__ __launch_bounds__(256)
void a_build(const unsigned short* __restrict__ h0, const unsigned short* __restrict__ h6,
             unsigned short* __restrict__ Ao)
{
    int bx = blockIdx.x;
    int P, H2, noff, pbase, pw, haspar; size_t aoff;
    if (bx < 1600)      { P = 1600; H2 = 40; noff = 0;    pbase = 1600; pw = 20; haspar = 1; aoff = 0; }
    else if (bx < 2000) { P = 400;  H2 = 20; noff = 1600; pbase = 2000; pw = 10; haspar = 1; aoff = 12800ULL * 256; bx -= 1600; }
    else                { P = 100;  H2 = 10; noff = 2000; pbase = 0;    pw = 0;  haspar = 0; aoff = 16000ULL * 256; bx -= 2000; }
    const int gid = bx * 256 + threadIdx.x;
    const int m = gid >> 5, c0 = (gid & 31) << 3;
    const int b = m / P, pix = m - b * P;
    const size_t src = ((size_t)(b * NODES + noff + pix)) * 256 + c0;
    u16x8 x0 = *(const u16x8*)(h0 + src);
    u16x8 x6 = *(const u16x8*)(h6 + src);
    float v[8];
#pragma unroll
    for (int e = 0; e < 8; ++e) v[e] = bf2f(x0[e]) + bf2f(x6[e]);
    if (haspar) {
        int ii = pix / H2, jj = pix - ii * H2;
        size_t sp = ((size_t)(b * NODES + pbase + (ii >> 1) * pw + (jj >> 1))) * 256 + c0;
        u16x8 xp = *(const u16x8*)(h6 + sp);
#pragma unroll
        for (int e = 0; e < 8; ++e) v[e] += bf2f(xp[e]);
    }
    u16x8 r;
#pragma unroll
    for (int e = 0; e < 8; ++e) r[e] = f2bf(v[e]);
    *(u16x8*)(Ao + aoff + (size_t)m * 256 + c0) = r;
}

// ---------------------------------------------------------------------------
// convT2x2, role-swapped: A = tW^T (rows = Cout*4, k-contig), B = pixel rows.
// C[row=(o,di,dj)][col=pixel] -> lane holds the 4 (di,dj) of one o at one
// pixel -> float2 writes contiguous across 16 lanes.  + bias + feat residual.
// ---------------------------------------------------------------------------
template<int P, int H2>
__global__ __launch_bounds__(256)
void convt_gemm(const unsigned short* __restrict__ WT, const unsigned short* __restrict__ Apix,
                const float* __restrict__ tb, const float* __restrict__ feat,
                float* __restrict__ out, int Cout, int Mpix)
{
    __shared__ __align__(16) unsigned short As[8192], Bs[8192];
    const int m0 = blockIdx.y << 7, n0 = blockIdx.x << 7;
    f32x4 acc[4][4];
#pragma unroll
    for (int fr = 0; fr < 4; ++fr)
#pragma unroll
        for (int fc = 0; fc < 4; ++fc) acc[fr][fc] = (f32x4){0.f, 0.f, 0.f, 0.f};

    gemm_core(WT, Apix, 256, m0, n0, Cout * 4 - 1, Mpix - 1, As, Bs, acc);

    const int lane = threadIdx.x & 63, w = threadIdx.x >> 6;
    const int wr = w >> 1, wc = w & 1;
    const int H = H2 * 2;
#pragma unroll
    for (int fc = 0; fc < 4; ++fc) {
        const int p_g = n0 + wc * 64 + fc * 16 + (lane & 15);
        if (p_g < Mpix) {
            const int b = p_g / P, pix = p_g - b * P;
            const int ii = pix / H2, jj = pix - ii * H2;
#pragma unroll
            for (int fr = 0; fr < 4; ++fr) {
                const int rb = m0 + wr * 64 + fr * 16 + (lane >> 4) * 4;
                const int o = rb >> 2;
                const float tbo = tb[o];
                size_t base = (((size_t)(b * Cout + o)) * H + 2 * ii) * H + 2 * jj;
                float2 f0 = *(const float2*)&feat[base];
                float2 r0; r0.x = acc[fr][fc][0] + tbo + f0.x; r0.y = acc[fr][fc][1] + tbo + f0.y;
                *(float2*)&out[base] = r0;
                float2 f1 = *(const float2*)&feat[base + H];
                float2 r1; r1.x = acc[fr][fc][2] + tbo + f1.x; r1.y = acc[fr][fc][3] + tbo + f1.y;
                *(float2*)&out[base + H] = r1;
            }
        }
    }
}

// ---------------------------------------------------------------------------
extern "C" void kernel_launch(void* const* d_in, const int* in_sizes, int n_in,
                              void* d_out, int out_size, void* d_ws, size_t ws_size,
                              hipStream_t stream)
{
    const float* feats[3] = { (const float*)d_in[1], (const float*)d_in[2], (const float*)d_in[3] };
    const float* gb[6];
    for (int l = 0; l < 6; ++l) gb[l] = (const float*)d_in[23 + 2 * l];
    const float* tb[3] = { (const float*)d_in[35], (const float*)d_in[37], (const float*)d_in[39] };

    // ---- workspace layout ----
    size_t off = 0;
    auto alloc = [&](size_t bytes) { size_t r = off; off = (off + bytes + 511) & ~(size_t)511; return r; };
    unsigned short* h0b  = (unsigned short*)((char*)d_ws + alloc(16800ULL * 256 * 2));
    unsigned short* hA   = (unsigned short*)((char*)d_ws + alloc(16800ULL * 256 * 2));
    unsigned short* hB   = (unsigned short*)((char*)d_ws + alloc(16800ULL * 256 * 2));
    unsigned short* dwb  = (unsigned short*)((char*)d_ws + alloc(917504ULL * 2));
    unsigned short* gWTb = (unsigned short*)((char*)d_ws + alloc(6ULL * 65536 * 2));
    unsigned short* tWTb = (unsigned short*)((char*)d_ws + alloc(3670016ULL * 2));
    float*          scshb= (float*)((char*)d_ws + alloc(3ULL * 512 * 4));
    const size_t fixedBytes = off;
    const bool big = ws_size >= fixedBytes + 52428800ULL + 1024;
    char* BIG = (char*)d_ws + off;
    unsigned short* Afeat  = (unsigned short*)BIG;    // conv phase
    unsigned short* Aconvt = (unsigned short*)BIG;    // convt phase

    // ---- feat0 passthrough ----
    hipMemcpyAsync(d_out, d_in[0], 52428800ULL * 4, hipMemcpyDeviceToDevice, stream);

    // ---- mega-prep (all weight conversion + BN) ----
    PrepArgs pa;
    pa.dw0 = (const float*)d_in[4];  pa.dw1 = (const float*)d_in[10]; pa.dw2 = (const float*)d_in[16];
    pa.gw0 = (const float*)d_in[22]; pa.gw1 = (const float*)d_in[24]; pa.gw2 = (const float*)d_in[26];
    pa.gw3 = (const float*)d_in[28]; pa.gw4 = (const float*)d_in[30]; pa.gw5 = (const float*)d_in[32];
    pa.tw0 = (const float*)d_in[34]; pa.tw1 = (const float*)d_in[36]; pa.tw2 = (const float*)d_in[38];
    pa.g0 = (const float*)d_in[6];  pa.g1 = (const float*)d_in[12]; pa.g2 = (const float*)d_in[18];
    pa.b0 = (const float*)d_in[7];  pa.b1 = (const float*)d_in[13]; pa.b2 = (const float*)d_in[19];
    pa.m0 = (const float*)d_in[8];  pa.m1 = (const float*)d_in[14]; pa.m2 = (const float*)d_in[20];
    pa.v0 = (const float*)d_in[9];  pa.v1 = (const float*)d_in[15]; pa.v2 = (const float*)d_in[21];
    pa.db0 = (const float*)d_in[5]; pa.db1 = (const float*)d_in[11]; pa.db2 = (const float*)d_in[17];
    pa.dwb = dwb; pa.gWTb = gWTb; pa.tWTb = tWTb; pa.scshb = scshb;
    mega_prep<<<dim3(4417), dim3(256), 0, stream>>>(pa);

    // ---- conv1x1 + BN + ReLU + pool (chunked by batch if ws is small) ----
    const int Ks[3] = {512, 1024, 2048};
    const int Hs[3] = {80, 40, 20};
    const int PPs[3] = {1600, 400, 100};
    const int noffs[3] = {0, 1600, 2000};
    const size_t dwoff[3] = {0, 131072, 393216};
    const int nch[3] = { big ? 1 : 4, big ? 1 : 2, 1 };
    for (int s = 0; s < 3; ++s) {
        const int H = Hs[s], HW = H * H, K = Ks[s];
        const int bPer = 8 / nch[s];
        const int rows = bPer * HW;
        for (int c = 0; c < nch[s]; ++c) {
            int b0 = c * bPer;
            feat_transpose<<<dim3(rows / 64, K / 64), dim3(256), 0, stream>>>(
                feats[s], Afeat, K, H, H, b0);
            dim3 grid(2, rows / 128);
            if (s == 0)
                conv_gemm<1600><<<grid, dim3(256), 0, stream>>>(Afeat, dwb + dwoff[s], scshb + s * 512, h0b, K, b0 * PPs[s], noffs[s], rows);
            else if (s == 1)
                conv_gemm<400><<<grid, dim3(256), 0, stream>>>(Afeat, dwb + dwoff[s], scshb + s * 512, h0b, K, b0 * PPs[s], noffs[s], rows);
            else
                conv_gemm<100><<<grid, dim3(256), 0, stream>>>(Afeat, dwb + dwoff[s], scshb + s * 512, h0b, K, b0 * PPs[s], noffs[s], rows);
        }
    }

    // ---- 6 fused GNN layers ----
    const int types[6] = {0, 0, 1, 1, 0, 0};
    const unsigned short* hin = h0b;
    unsigned short* houts[6] = {hA, hB, hA, hB, hA, hB};
    for (int l = 0; l < 6; ++l) {
        gnn_fused<<<dim3(263), dim3(256), 0, stream>>>(hin, gWTb + (size_t)l * 65536, gb[l], houts[l], types[l]);
        hin = houts[l];
    }
    unsigned short* h6 = hB;

    // ---- convT phase ----
    a_build<<<dim3(2100), dim3(256), 0, stream>>>(h0b, h6, Aconvt);

    float* out1 = (float*)d_out + 52428800;
    float* out2 = out1 + 26214400;
    float* out3 = out2 + 13107200;
    convt_gemm<1600, 40><<<dim3(100, 16), dim3(256), 0, stream>>>(
        tWTb,           Aconvt,                  tb[0], feats[0], out1, 512, 12800);
    convt_gemm<400, 20><<<dim3(25, 32), dim3(256), 0, stream>>>(
        tWTb + 524288,  Aconvt + 12800ULL * 256, tb[1], feats[1], out2, 1024, 3200);
    convt_gemm<100, 10><<<dim3(7, 64), dim3(256), 0, stream>>>(
        tWTb + 1572864, Aconvt + 16000ULL * 256, tb[2], feats[2], out3, 2048, 800);
}

// Round 4
// 500.439 us; speedup vs baseline: 3.9332x; 1.1457x over previous
//
#include <hip/hip_runtime.h>
#include <cstdint>

#define NODES 2100

typedef __attribute__((ext_vector_type(8))) __bf16 bf16x8;
typedef __attribute__((ext_vector_type(4))) float f32x4;
typedef __attribute__((ext_vector_type(8))) unsigned short u16x8;

__device__ inline float bf2f(unsigned short s) { return __uint_as_float(((unsigned)s) << 16); }
__device__ inline unsigned short f2bf(float f) {
    unsigned u = __float_as_uint(f);
    u += 0x7fff + ((u >> 16) & 1);          // RNE
    return (unsigned short)(u >> 16);
}
__device__ inline void gload16(const unsigned short* g, void* lds) {
    __builtin_amdgcn_global_load_lds(
        (const __attribute__((address_space(1))) void*)g,
        (__attribute__((address_space(3))) void*)lds, 16, 0, 0);
}

// ---------------------------------------------------------------------------
// Shared MFMA GEMM core (convt only now), 128x128 tile, BK=64, XOR-swizzled
// LDS both sides (linear dest + pre-swizzled source + swizzled read).
// ---------------------------------------------------------------------------
__device__ __attribute__((always_inline)) inline
void gemm_core(const unsigned short* __restrict__ A, const unsigned short* __restrict__ B,
               int K, int m0, int n0, int mClamp, int nClamp,
               unsigned short* As, unsigned short* Bs, f32x4 acc[4][4])
{
    const int t = threadIdx.x, lane = t & 63, w = t >> 6;
    const int wr = w >> 1, wc = w & 1;
    const int sx = (lane & 7) << 4;
    for (int k0 = 0; k0 < K; k0 += 64) {
#pragma unroll
        for (int i = 0; i < 4; ++i) {
            int LO  = ((i << 8) + t) << 4;
            int row = LO >> 7;
            int kb  = (LO & 127) ^ ((row & 7) << 4);
            int ke  = kb >> 1;
            int ra = m0 + row; if (ra > mClamp) ra = mClamp;
            int rb = n0 + row; if (rb > nClamp) rb = nClamp;
            gload16(A + (size_t)ra * K + k0 + ke, (char*)As + LO);
            gload16(B + (size_t)rb * K + k0 + ke, (char*)Bs + LO);
        }
        asm volatile("s_waitcnt vmcnt(0)" ::: "memory");
        __syncthreads();
#pragma unroll
        for (int kk = 0; kk < 2; ++kk) {
            bf16x8 a[4], bb[4];
#pragma unroll
            for (int f = 0; f < 4; ++f) {
                int pa = (((wr * 64 + f * 16 + (lane & 15)) << 7) + kk * 64 + ((lane >> 4) << 4)) ^ sx;
                int pb = (((wc * 64 + f * 16 + (lane & 15)) << 7) + kk * 64 + ((lane >> 4) << 4)) ^ sx;
                a[f]  = *(const bf16x8*)((const char*)As + pa);
                bb[f] = *(const bf16x8*)((const char*)Bs + pb);
            }
#pragma unroll
            for (int fr = 0; fr < 4; ++fr)
#pragma unroll
                for (int fc = 0; fc < 4; ++fc)
                    acc[fr][fc] = __builtin_amdgcn_mfma_f32_16x16x32_bf16(a[fr], bb[fc], acc[fr][fc], 0, 0, 0);
        }
        __syncthreads();
    }
}

// ---------------------------------------------------------------------------
// mega-prep: all weight conversions/transposes + BN scale/shift in ONE launch
// ---------------------------------------------------------------------------
struct PrepArgs {
    const float *dw0, *dw1, *dw2;
    const float *gw0, *gw1, *gw2, *gw3, *gw4, *gw5;
    const float *tw0, *tw1, *tw2;
    const float *g0, *g1, *g2, *b0, *b1, *b2, *m0, *m1, *m2, *v0, *v1, *v2, *db0, *db1, *db2;
    unsigned short *dwb, *gWTb, *tWTb;
    float *scshb;
};

__device__ inline void transpose32(const float* __restrict__ in, unsigned short* __restrict__ outT,
                                   int Ccols, int c0, int r0)
{
    __shared__ float T[32][33];
    const int tx = threadIdx.x & 31, ty = threadIdx.x >> 5;
#pragma unroll
    for (int i = 0; i < 4; ++i)
        T[ty + i * 8][tx] = in[(size_t)(r0 + ty + i * 8) * Ccols + c0 + tx];
    __syncthreads();
#pragma unroll
    for (int i = 0; i < 4; ++i)
        outT[(size_t)(c0 + ty + i * 8) * 256 + r0 + tx] = f2bf(T[tx][ty + i * 8]);
}

__global__ __launch_bounds__(256)
void mega_prep(PrepArgs a)
{
    const int bid = blockIdx.x, t = threadIdx.x;
    if (bid < 448) {                           // dw convert (concatenated)
        int idx = (bid * 256 + t) * 8;
        const float* src;
        int loc;
        if (idx < 131072)      { src = a.dw0; loc = idx; }
        else if (idx < 393216) { src = a.dw1; loc = idx - 131072; }
        else                   { src = a.dw2; loc = idx - 393216; }
        float4 x = *(const float4*)(src + loc);
        float4 y = *(const float4*)(src + loc + 4);
        u16x8 r;
        r[0] = f2bf(x.x); r[1] = f2bf(x.y); r[2] = f2bf(x.z); r[3] = f2bf(x.w);
        r[4] = f2bf(y.x); r[5] = f2bf(y.y); r[6] = f2bf(y.z); r[7] = f2bf(y.w);
        *(u16x8*)(a.dwb + idx) = r;
    } else if (bid < 832) {                    // gW transpose: 6 x (8x8 blocks)
        int gid = bid - 448;
        int l = gid >> 6, sb = gid & 63;
        const float* gw[6] = {a.gw0, a.gw1, a.gw2, a.gw3, a.gw4, a.gw5};
        transpose32(gw[l], a.gWTb + (size_t)l * 65536, 256, (sb & 7) << 5, (sb >> 3) << 5);
    } else if (bid < 4416) {                   // tW transpose
        int gid = bid - 832;
        const float* tw; unsigned short* dst; int ncx, loc;
        if (gid < 512)       { tw = a.tw0; dst = a.tWTb;           ncx = 64;  loc = gid; }
        else if (gid < 1536) { tw = a.tw1; dst = a.tWTb + 524288;  ncx = 128; loc = gid - 512; }
        else                 { tw = a.tw2; dst = a.tWTb + 1572864; ncx = 256; loc = gid - 1536; }
        int cx = loc % ncx, ry = loc / ncx;
        transpose32(tw, dst, ncx * 32, cx << 5, ry << 5);
    } else {                                   // BN scale/shift
        const float* g[3]  = {a.g0, a.g1, a.g2};
        const float* b[3]  = {a.b0, a.b1, a.b2};
        const float* m[3]  = {a.m0, a.m1, a.m2};
        const float* v[3]  = {a.v0, a.v1, a.v2};
        const float* db[3] = {a.db0, a.db1, a.db2};
        for (int s = 0; s < 3; ++s) {
            float sc = g[s][t] * rsqrtf(v[s][t] + 1e-5f);
            a.scshb[s * 512 + t] = sc;
            a.scshb[s * 512 + 256 + t] = (db[s][t] - m[s][t]) * sc + b[s][t];
        }
    }
}

// ---------------------------------------------------------------------------
// Fused conv1x1: transpose-stage fp32 feat directly into swizzled LDS,
// MFMA vs weights (BM=64 pixels x BN=256 outputs, all scales in one launch),
// BN+ReLU+pool epilogue -> h0 bf16 node-major.  A read exactly once from HBM.
// ---------------------------------------------------------------------------
struct ConvArgs {
    const float* feat[3];
    const unsigned short* dwb[3];
    const float* scsh[3];
    unsigned short* h0out;
};

__global__ __launch_bounds__(256)
void conv_fused(ConvArgs ca)
{
    __shared__ __align__(16) unsigned short As[64 * 64];   // swizzled, 8 KB
    __shared__ __align__(16) unsigned short Bs[256 * 64];  // swizzled, 32 KB
    int bx = blockIdx.x;
    int s, mt;
    if (bx < 800)       { s = 0; mt = bx; }
    else if (bx < 1000) { s = 1; mt = bx - 800; }
    else                { s = 2; mt = bx - 1000; }
    const int Kc[3]  = {512, 1024, 2048};
    const int Wc[3]  = {80, 40, 20};
    const int PPc[3] = {1600, 400, 100};
    const int nfc[3] = {0, 1600, 2000};
    const int K = Kc[s], W = Wc[s], W2 = W >> 1, HW = W * W, PP = PPc[s], noff = nfc[s];
    const float* feat = ca.feat[s];
    const unsigned short* dw = ca.dwb[s];
    const float* scsh = ca.scsh[s];

    const int t = threadIdx.x, lane = t & 63, w = t >> 6;
    const int sx = (lane & 7) << 4;

    // --- per-thread A-source address (m = (b,pooled,sub) pixel order) ---
    const int ml = t & 63;                     // m_local
    const int kw = t >> 6;                     // k phase 0..3
    const int graw = mt * 64 + ml;             // global m row
    const int b = graw / HW;
    const int rem = graw - b * HW;
    const int pooled = rem >> 2, sub = rem & 3;
    const int pi = pooled / W2, pj = pooled - pi * W2;
    const int i = pi * 2 + (sub >> 1), j = pj * 2 + (sub & 1);
    const float* src = feat + (size_t)b * K * HW + (size_t)i * W + j;
    const int sxm = (ml & 7) << 3;             // short-index XOR for row ml

    f32x4 acc[4][4];
#pragma unroll
    for (int fr = 0; fr < 4; ++fr)
#pragma unroll
        for (int fc = 0; fc < 4; ++fc) acc[fr][fc] = (f32x4){0.f, 0.f, 0.f, 0.f};

    for (int k0 = 0; k0 < K; k0 += 64) {
        // B stage: 256 outputs x 64 k, swizzled source -> linear LDS
#pragma unroll
        for (int it = 0; it < 8; ++it) {
            int LO = ((it << 8) + t) << 4;
            int row = LO >> 7;
            int kb = (LO & 127) ^ ((row & 7) << 4);
            gload16(dw + (size_t)row * K + k0 + (kb >> 1), (char*)Bs + LO);
        }
        // A stage: transpose fp32 feat -> bf16 swizzled LDS (16 strided k per thread)
        float v[16];
#pragma unroll
        for (int it = 0; it < 16; ++it)
            v[it] = src[(size_t)(k0 + it * 4 + kw) * HW];
#pragma unroll
        for (int it = 0; it < 16; ++it) {
            int k_l = it * 4 + kw;
            As[(ml << 6) + (k_l ^ sxm)] = f2bf(v[it]);
        }
        asm volatile("s_waitcnt vmcnt(0)" ::: "memory");
        __syncthreads();
#pragma unroll
        for (int kk = 0; kk < 2; ++kk) {
            bf16x8 a[4], bb[4];
#pragma unroll
            for (int f = 0; f < 4; ++f) {
                int pa = (((f * 16 + (lane & 15)) << 7) + kk * 64 + ((lane >> 4) << 4)) ^ sx;
                int pb = (((w * 64 + f * 16 + (lane & 15)) << 7) + kk * 64 + ((lane >> 4) << 4)) ^ sx;
                a[f]  = *(const bf16x8*)((const char*)As + pa);
                bb[f] = *(const bf16x8*)((const char*)Bs + pb);
            }
#pragma unroll
            for (int fr = 0; fr < 4; ++fr)
#pragma unroll
                for (int fc = 0; fc < 4; ++fc)
                    acc[fr][fc] = __builtin_amdgcn_mfma_f32_16x16x32_bf16(a[fr], bb[fc], acc[fr][fc], 0, 0, 0);
        }
        __syncthreads();
    }

    // epilogue: BN + ReLU + 2x2 pool (4 acc regs = 4 subs of one pooled pixel)
#pragma unroll
    for (int fc = 0; fc < 4; ++fc) {
        const int o = w * 64 + fc * 16 + (lane & 15);
        const float sc = scsh[o], sh = scsh[256 + o];
#pragma unroll
        for (int fr = 0; fr < 4; ++fr) {
            const int mrow = mt * 64 + fr * 16 + (lane >> 4) * 4;
            const int q = mrow >> 2;
            const int bi = q / PP;
            const int node = noff + (q - bi * PP);
            float sum = 0.f;
#pragma unroll
            for (int r = 0; r < 4; ++r)
                sum += fmaxf(acc[fr][fc][r] * sc + sh, 0.f);
            ca.h0out[((size_t)(bi * NODES + node)) * 256 + o] = f2bf(sum * 0.25f);
        }
    }
}

// ---------------------------------------------------------------------------
// Fused GNN layer, BM=32 (525 blocks, 2 blocks/CU): gather -> swizzled LDS,
// MFMA vs weights.  out = relu(mean_nbr(h) @ W + b).
// ---------------------------------------------------------------------------
__global__ __launch_bounds__(256)
void gnn_fused(const unsigned short* __restrict__ h, const unsigned short* __restrict__ BT,
               const float* __restrict__ bias, unsigned short* __restrict__ out, int hier)
{
    __shared__ __align__(16) unsigned short As[32 * 64];   // swizzled, 4 KB
    __shared__ __align__(16) unsigned short Bs[256 * 64];  // swizzled, 32 KB
    const int t = threadIdx.x, lane = t & 63, w = t >> 6;
    const int r0 = blockIdx.x << 5;
    const int myrow = t >> 3, q = t & 7;      // 8 threads per row, 8 k each
    const int grow = r0 + myrow;              // 16800 = 525*32, no tail
    const int b = grow / NODES;
    const int n = grow - b * NODES;

    int gw, off;
    if (n < 1600)      { gw = 40; off = 0; }
    else if (n < 2000) { gw = 20; off = 1600; }
    else               { gw = 10; off = 2000; }
    const int li = (n - off) / gw;
    const int lj = (n - off) - li * gw;
    int nbr[9]; int cnt = 0;
    if (!hier) {
#pragma unroll
        for (int di = -1; di <= 1; ++di)
#pragma unroll
            for (int dj = -1; dj <= 1; ++dj) {
                int ii = li + di, jj = lj + dj;
                if (ii >= 0 && ii < gw && jj >= 0 && jj < gw) nbr[cnt++] = off + ii * gw + jj;
            }
    } else {
        nbr[cnt++] = n;
        if (off == 0) {
            nbr[cnt++] = 1600 + (li >> 1) * 20 + (lj >> 1);
        } else if (off == 1600) {
            nbr[cnt++] = 2000 + (li >> 1) * 10 + (lj >> 1);
#pragma unroll
            for (int di = 0; di < 2; ++di)
#pragma unroll
                for (int dj = 0; dj < 2; ++dj)
                    nbr[cnt++] = ((li << 1) + di) * 40 + ((lj << 1) + dj);
        } else {
#pragma unroll
            for (int di = 0; di < 2; ++di)
#pragma unroll
                for (int dj = 0; dj < 2; ++dj)
                    nbr[cnt++] = 1600 + ((li << 1) + di) * 20 + ((lj << 1) + dj);
        }
    }
    int nboff[9];
#pragma unroll
    for (int e = 0; e < 9; ++e)
        nboff[e] = (b * NODES + nbr[e < cnt ? e : 0]) * 256 + q * 8;
    const float inv = 1.0f / (float)cnt;
    const int sx = (lane & 7) << 4;
    const int awr = (myrow << 6) + ((q ^ (myrow & 7)) << 3);  // swizzled write slot

    f32x4 acc[2][4];
#pragma unroll
    for (int fr = 0; fr < 2; ++fr)
#pragma unroll
        for (int fc = 0; fc < 4; ++fc) acc[fr][fc] = (f32x4){0.f, 0.f, 0.f, 0.f};

    for (int k0 = 0; k0 < 256; k0 += 64) {
        // B stage (weights, swizzled source)
#pragma unroll
        for (int it = 0; it < 8; ++it) {
            int LO = ((it << 8) + t) << 4;
            int row = LO >> 7;
            int kb = (LO & 127) ^ ((row & 7) << 4);
            gload16(BT + (size_t)row * 256 + k0 + (kb >> 1), (char*)Bs + LO);
        }
        // A gather: mean of neighbor rows, 8 k per thread
        float sacc[8] = {0, 0, 0, 0, 0, 0, 0, 0};
        for (int e = 0; e < cnt; ++e) {
            u16x8 vv = *(const u16x8*)(h + nboff[e] + k0);
#pragma unroll
            for (int jj = 0; jj < 8; ++jj) sacc[jj] += bf2f(vv[jj]);
        }
        u16x8 o0;
#pragma unroll
        for (int jj = 0; jj < 8; ++jj) o0[jj] = f2bf(sacc[jj] * inv);
        *(u16x8*)&As[awr] = o0;

        asm volatile("s_waitcnt vmcnt(0)" ::: "memory");
        __syncthreads();
#pragma unroll
        for (int kk = 0; kk < 2; ++kk) {
            bf16x8 a[2], bb[4];
#pragma unroll
            for (int f = 0; f < 2; ++f) {
                int pa = (((f * 16 + (lane & 15)) << 7) + kk * 64 + ((lane >> 4) << 4)) ^ sx;
                a[f] = *(const bf16x8*)((const char*)As + pa);
            }
#pragma unroll
            for (int f = 0; f < 4; ++f) {
                int pb = (((w * 64 + f * 16 + (lane & 15)) << 7) + kk * 64 + ((lane >> 4) << 4)) ^ sx;
                bb[f] = *(const bf16x8*)((const char*)Bs + pb);
            }
#pragma unroll
            for (int fr = 0; fr < 2; ++fr)
#pragma unroll
                for (int fc = 0; fc < 4; ++fc)
                    acc[fr][fc] = __builtin_amdgcn_mfma_f32_16x16x32_bf16(a[fr], bb[fc], acc[fr][fc], 0, 0, 0);
        }
        __syncthreads();
    }

#pragma unroll
    for (int fc = 0; fc < 4; ++fc) {
        const int d = w * 64 + fc * 16 + (lane & 15);
        const float bv = bias[d];
#pragma unroll
        for (int fr = 0; fr < 2; ++fr) {
            int rb = r0 + fr * 16 + (lane >> 4) * 4;
#pragma unroll
            for (int r = 0; r < 4; ++r)
                out[(size_t)(rb + r) * 256 + d] = f2bf(fmaxf(acc[fr][fc][r] + bv, 0.f));
        }
    }
}

// ---------------------------------------------------------------------------
// convT A-matrix build: a[m][c] = h0 + h6 (+ h6[parent]), bf16.  ONE launch.
// ---------------------------------------------------------------------------
__global__ __launch_bounds__(256)
void a_build(const unsigned short* __restrict__ h0, const unsigned short* __restrict__ h6,
             unsigned short* __restrict__ Ao)
{
    int bx = blockIdx.x;
    int P, H2, noff, pbase, pw, haspar; size_t aoff;
    if (bx < 1600)      { P = 1600; H2 = 40; noff = 0;    pbase = 1600; pw = 20; haspar = 1; aoff = 0; }
    else if (bx < 2000) { P = 400;  H2 = 20; noff = 1600; pbase = 2000; pw = 10; haspar = 1; aoff = 12800ULL * 256; bx -= 1600; }
    else                { P = 100;  H2 = 10; noff = 2000; pbase = 0;    pw = 0;  haspar = 0; aoff = 16000ULL * 256; bx -= 2000; }
    const int gid = bx * 256 + threadIdx.x;
    const int m = gid >> 5, c0 = (gid & 31) << 3;
    const int b = m / P, pix = m - b * P;
    const size_t src = ((size_t)(b * NODES + noff + pix)) * 256 + c0;
    u16x8 x0 = *(const u16x8*)(h0 + src);
    u16x8 x6 = *(const u16x8*)(h6 + src);
    float v[8];
#pragma unroll
    for (int e = 0; e < 8; ++e) v[e] = bf2f(x0[e]) + bf2f(x6[e]);
    if (haspar) {
        int ii = pix / H2, jj = pix - ii * H2;
        size_t sp = ((size_t)(b * NODES + pbase + (ii >> 1) * pw + (jj >> 1))) * 256 + c0;
        u16x8 xp = *(const u16x8*)(h6 + sp);
#pragma unroll
        for (int e = 0; e < 8; ++e) v[e] += bf2f(xp[e]);
    }
    u16x8 r;
#pragma unroll
    for (int e = 0; e < 8; ++e) r[e] = f2bf(v[e]);
    *(u16x8*)(Ao + aoff + (size_t)m * 256 + c0) = r;
}

// ---------------------------------------------------------------------------
// convT2x2, role-swapped, ALL SCALES IN ONE LAUNCH.
// A = tW^T (rows = Cout*4), B = pixel rows; lane's 4 regs = the 2x2 block of
// one o at one pixel -> float2 writes; + bias + feat residual.
// ---------------------------------------------------------------------------
struct ConvtArgs {
    const unsigned short* WT[3];
    const unsigned short* Apix[3];
    const float* tb[3];
    const float* feat[3];
    float* out[3];
};

__global__ __launch_bounds__(256)
void convt_fused(ConvtArgs ct)
{
    __shared__ __align__(16) unsigned short As[8192], Bs[8192];
    int bx = blockIdx.x;
    int s, px, my;
    if (bx < 1600)      { s = 0; px = bx % 100; my = bx / 100; }
    else if (bx < 2400) { s = 1; bx -= 1600; px = bx % 25; my = bx / 25; }
    else                { s = 2; bx -= 2400; px = bx % 7;  my = bx / 7; }
    const int Pc[3]  = {1600, 400, 100};
    const int H2c[3] = {40, 20, 10};
    const int Cc[3]  = {512, 1024, 2048};
    const int Mc[3]  = {12800, 3200, 800};
    const int P = Pc[s], H2 = H2c[s], Cout = Cc[s], Mpix = Mc[s];
    const int m0 = my << 7, n0 = px << 7;

    f32x4 acc[4][4];
#pragma unroll
    for (int fr = 0; fr < 4; ++fr)
#pragma unroll
        for (int fc = 0; fc < 4; ++fc) acc[fr][fc] = (f32x4){0.f, 0.f, 0.f, 0.f};

    gemm_core(ct.WT[s], ct.Apix[s], 256, m0, n0, Cout * 4 - 1, Mpix - 1, As, Bs, acc);

    const int lane = threadIdx.x & 63, w = threadIdx.x >> 6;
    const int wr = w >> 1, wc = w & 1;
    const int H = H2 * 2;
    const float* feat = ct.feat[s];
    float* out = ct.out[s];
#pragma unroll
    for (int fc = 0; fc < 4; ++fc) {
        const int p_g = n0 + wc * 64 + fc * 16 + (lane & 15);
        if (p_g < Mpix) {
            const int b = p_g / P, pix = p_g - b * P;
            const int ii = pix / H2, jj = pix - ii * H2;
#pragma unroll
            for (int fr = 0; fr < 4; ++fr) {
                const int rb = m0 + wr * 64 + fr * 16 + (lane >> 4) * 4;
                const int o = rb >> 2;
                const float tbo = ct.tb[s][o];
                size_t base = (((size_t)(b * Cout + o)) * H + 2 * ii) * H + 2 * jj;
                float2 f0 = *(const float2*)&feat[base];
                float2 r0v; r0v.x = acc[fr][fc][0] + tbo + f0.x; r0v.y = acc[fr][fc][1] + tbo + f0.y;
                *(float2*)&out[base] = r0v;
                float2 f1 = *(const float2*)&feat[base + H];
                float2 r1v; r1v.x = acc[fr][fc][2] + tbo + f1.x; r1v.y = acc[fr][fc][3] + tbo + f1.y;
                *(float2*)&out[base + H] = r1v;
            }
        }
    }
}

// ---------------------------------------------------------------------------
extern "C" void kernel_launch(void* const* d_in, const int* in_sizes, int n_in,
                              void* d_out, int out_size, void* d_ws, size_t ws_size,
                              hipStream_t stream)
{
    const float* feats[3] = { (const float*)d_in[1], (const float*)d_in[2], (const float*)d_in[3] };
    const float* gb[6];
    for (int l = 0; l < 6; ++l) gb[l] = (const float*)d_in[23 + 2 * l];
    const float* tb[3] = { (const float*)d_in[35], (const float*)d_in[37], (const float*)d_in[39] };

    // ---- workspace layout ----
    size_t off = 0;
    auto alloc = [&](size_t bytes) { size_t r = off; off = (off + bytes + 511) & ~(size_t)511; return r; };
    unsigned short* h0b  = (unsigned short*)((char*)d_ws + alloc(16800ULL * 256 * 2));
    unsigned short* hA   = (unsigned short*)((char*)d_ws + alloc(16800ULL * 256 * 2));
    unsigned short* hB   = (unsigned short*)((char*)d_ws + alloc(16800ULL * 256 * 2));
    unsigned short* dwb  = (unsigned short*)((char*)d_ws + alloc(917504ULL * 2));
    unsigned short* gWTb = (unsigned short*)((char*)d_ws + alloc(6ULL * 65536 * 2));
    unsigned short* tWTb = (unsigned short*)((char*)d_ws + alloc(3670016ULL * 2));
    float*          scshb= (float*)((char*)d_ws + alloc(3ULL * 512 * 4));
    unsigned short* Aconvt = (unsigned short*)((char*)d_ws + off);   // 8.6 MB

    // ---- feat0 passthrough ----
    hipMemcpyAsync(d_out, d_in[0], 52428800ULL * 4, hipMemcpyDeviceToDevice, stream);

    // ---- mega-prep (all weight conversion + BN) ----
    PrepArgs pa;
    pa.dw0 = (const float*)d_in[4];  pa.dw1 = (const float*)d_in[10]; pa.dw2 = (const float*)d_in[16];
    pa.gw0 = (const float*)d_in[22]; pa.gw1 = (const float*)d_in[24]; pa.gw2 = (const float*)d_in[26];
    pa.gw3 = (const float*)d_in[28]; pa.gw4 = (const float*)d_in[30]; pa.gw5 = (const float*)d_in[32];
    pa.tw0 = (const float*)d_in[34]; pa.tw1 = (const float*)d_in[36]; pa.tw2 = (const float*)d_in[38];
    pa.g0 = (const float*)d_in[6];  pa.g1 = (const float*)d_in[12]; pa.g2 = (const float*)d_in[18];
    pa.b0 = (const float*)d_in[7];  pa.b1 = (const float*)d_in[13]; pa.b2 = (const float*)d_in[19];
    pa.m0 = (const float*)d_in[8];  pa.m1 = (const float*)d_in[14]; pa.m2 = (const float*)d_in[20];
    pa.v0 = (const float*)d_in[9];  pa.v1 = (const float*)d_in[15]; pa.v2 = (const float*)d_in[21];
    pa.db0 = (const float*)d_in[5]; pa.db1 = (const float*)d_in[11]; pa.db2 = (const float*)d_in[17];
    pa.dwb = dwb; pa.gWTb = gWTb; pa.tWTb = tWTb; pa.scshb = scshb;
    mega_prep<<<dim3(4417), dim3(256), 0, stream>>>(pa);

    // ---- fused conv1x1 + BN + ReLU + pool (all scales, one launch) ----
    ConvArgs ca;
    ca.feat[0] = feats[0]; ca.feat[1] = feats[1]; ca.feat[2] = feats[2];
    ca.dwb[0] = dwb; ca.dwb[1] = dwb + 131072; ca.dwb[2] = dwb + 393216;
    ca.scsh[0] = scshb; ca.scsh[1] = scshb + 512; ca.scsh[2] = scshb + 1024;
    ca.h0out = h0b;
    conv_fused<<<dim3(1050), dim3(256), 0, stream>>>(ca);

    // ---- 6 fused GNN layers ----
    const int types[6] = {0, 0, 1, 1, 0, 0};
    const unsigned short* hin = h0b;
    unsigned short* houts[6] = {hA, hB, hA, hB, hA, hB};
    for (int l = 0; l < 6; ++l) {
        gnn_fused<<<dim3(525), dim3(256), 0, stream>>>(hin, gWTb + (size_t)l * 65536, gb[l], houts[l], types[l]);
        hin = houts[l];
    }
    unsigned short* h6 = hB;

    // ---- convT phase ----
    a_build<<<dim3(2100), dim3(256), 0, stream>>>(h0b, h6, Aconvt);

    ConvtArgs ct;
    ct.WT[0] = tWTb; ct.WT[1] = tWTb + 524288; ct.WT[2] = tWTb + 1572864;
    ct.Apix[0] = Aconvt; ct.Apix[1] = Aconvt + 12800ULL * 256; ct.Apix[2] = Aconvt + 16000ULL * 256;
    ct.tb[0] = tb[0]; ct.tb[1] = tb[1]; ct.tb[2] = tb[2];
    ct.feat[0] = feats[0]; ct.feat[1] = feats[1]; ct.feat[2] = feats[2];
    ct.out[0] = (float*)d_out + 52428800;
    ct.out[1] = (float*)d_out + 52428800 + 26214400;
    ct.out[2] = (float*)d_out + 52428800 + 26214400 + 13107200;
    convt_fused<<<dim3(2848), dim3(256), 0, stream>>>(ct);
}